// Round 15
// baseline (433.066 us; speedup 1.0000x reference)
//
#include <hip/hip_runtime.h>
#include <hip/hip_bf16.h>

typedef unsigned short u16;
typedef unsigned int   u32;

// Problem constants: B=4, S=2048, D=1024, H=16, HD=64
constexpr int B = 4, S = 2048, D = 1024, H = 16, HD = 64;
constexpr int M = B * S;                    // 8192
constexpr size_t TEN = (size_t)M * D;       // elems per q/k/v tensor (8.4M)

using bf16x8 = __attribute__((ext_vector_type(8))) short;
using f32x4  = __attribute__((ext_vector_type(4))) float;

__device__ __forceinline__ u16 f2bf(float f) {      // RNE f32 -> bf16
    u32 u = __float_as_uint(f);
    u += 0x7fffu + ((u >> 16) & 1u);
    return (u16)(u >> 16);
}
__device__ __forceinline__ u32 pack2(u16 a, u16 b) { return (u32)a | ((u32)b << 16); }

// raw v_exp_f32: D = 2^S0 (ISA §3). Avoids OCML exp2 slow-path branches.
__device__ __forceinline__ float fexp2(float x) {
    float r; asm("v_exp_f32 %0, %1" : "=v"(r) : "v"(x)); return r;
}

// Async global->LDS, 16B per lane. LDS dest is the WAVE-UNIFORM base;
// HW writes lane i at base + i*16. Source addr is per-lane.
__device__ __forceinline__ void gll16(const u16* gsrc, u16* ldst) {
    __builtin_amdgcn_global_load_lds(
        (const __attribute__((address_space(1))) u32*)gsrc,
        (__attribute__((address_space(3))) u32*)ldst,
        16, 0, 0);
}

// ---------------------------------------------------------------------------
// Kernel 0: convert x -> bf16 and Wq|Wk|Wv -> bf16. Unchanged from R13.
// ---------------------------------------------------------------------------
constexpr size_t NX8 = TEN / 8;             // 1,048,576 x-chunks
constexpr size_t NW8 = (size_t)D * D / 8;   // 131,072 chunks per W

__global__ __launch_bounds__(256) void convert_kernel(
    const float* __restrict__ x,
    const float* __restrict__ Wq, const float* __restrict__ Wk,
    const float* __restrict__ Wv,
    u16* __restrict__ xbf, u16* __restrict__ wbf)
{
    size_t i = (size_t)blockIdx.x * 256 + threadIdx.x;
    if (i < NX8) {
        float4 f0 = *((const float4*)x + i * 2);
        float4 f1 = *((const float4*)x + i * 2 + 1);
        float f[8] = {f0.x, f0.y, f0.z, f0.w, f1.x, f1.y, f1.z, f1.w};
        u16 h[8];
        #pragma unroll
        for (int e = 0; e < 8; ++e) h[e] = f2bf(f[e]);
        *(uint4*)(xbf + i * 8) = make_uint4(pack2(h[0],h[1]), pack2(h[2],h[3]),
                                            pack2(h[4],h[5]), pack2(h[6],h[7]));
    } else if (i < NX8 + 3 * NW8) {
        size_t j = i - NX8;
        const float* Wsrc;
        size_t jj;
        if (j < NW8)            { Wsrc = Wq; jj = j; }
        else if (j < 2 * NW8)   { Wsrc = Wk; jj = j - NW8; }
        else                    { Wsrc = Wv; jj = j - 2 * NW8; }
        float4 f0 = *((const float4*)Wsrc + jj * 2);
        float4 f1 = *((const float4*)Wsrc + jj * 2 + 1);
        float f[8] = {f0.x, f0.y, f0.z, f0.w, f1.x, f1.y, f1.z, f1.w};
        u16 h[8];
        #pragma unroll
        for (int e = 0; e < 8; ++e) h[e] = f2bf(f[e]);
        *(uint4*)(wbf + j * 8) = make_uint4(pack2(h[0],h[1]), pack2(h[2],h[3]),
                                            pack2(h[4],h[5]), pack2(h[6],h[7]));
    }
}

// ---------------------------------------------------------------------------
// Kernel 1: QKV projection via bf16 MFMA. R15: GBM 128->256 (8 waves, 512
// threads): per-thread staging 4->3 gll16/tile, W L2 traffic halved, half
// the blocks. Per-wave formulas identical to R13/R14 (arow = w*32+...).
// Occupancy: 2 blocks x 8 waves = 16 waves/CU (same as before); LDS 48KB.
// ---------------------------------------------------------------------------
constexpr int GBM = 256, GBN = 128, GBK = 32;
constexpr int NKT = D / GBK;                 // 32 k-tiles

__global__ __launch_bounds__(512, 4) void qkv_proj_kernel(
    const u16* __restrict__ xbf, const u16* __restrict__ wbf,
    const float* __restrict__ bq, const float* __restrict__ bk,
    const float* __restrict__ bv,
    u16* __restrict__ wsq, u16* __restrict__ wsk, u16* __restrict__ wvt)
{
    // XCD-chunk decode: 768 blocks; xcd owns m-strips xcd*4..xcd*4+3.
    const int lin    = blockIdx.x;            // 0..767
    const int xcd    = lin & 7;
    const int local  = lin >> 3;              // 0..95
    const int wg     = local >> 2;            // 0..23 : (zi,ny)
    const int zi     = wg >> 3;               // 0..2
    const int ny     = wg & 7;                // 0..7
    const int mstrip = xcd * 4 + (local & 3); // 0..31

    const u16* __restrict__ Wz = wbf + (size_t)zi * D * D;
    const float* __restrict__ bias = (zi == 0) ? bq : (zi == 1) ? bk : bv;

    const int m0 = mstrip * GBM;
    const int n0 = ny * GBN;                  // spans heads n0/64, n0/64+1
    const int h0 = n0 >> 6;
    const int tid = threadIdx.x;
    const int w = tid >> 6, lane = tid & 63;  // 8 waves
    const int l15 = lane & 15, lg = lane >> 4;

    __shared__ __align__(16) u16 Ah[2][GBM * GBK];   // 2 x 16KB
    __shared__ __align__(16) u16 Bt[2][GBN * GBK];   // 2 x 8KB

    const u16* __restrict__ xb_b = xbf + (size_t)m0 * D;
    const u16* __restrict__ wz_b = Wz + (size_t)n0 * D;

    f32x4 acc[2][8];
    #pragma unroll
    for (int mi = 0; mi < 2; ++mi)
        #pragma unroll
        for (int ni = 0; ni < 8; ++ni) acc[mi][ni] = (f32x4){0.f,0.f,0.f,0.f};

    // A: 1024 chunks (2/thread); B: 512 chunks (1/thread).
    auto stage = [&](int kt, int bb) {
        const int kofs = kt * GBK;
        #pragma unroll
        for (int p = 0; p < 2; ++p) {
            int c = w * 128 + p * 64 + lane;          // 0..1023
            int r = c >> 2, s = c & 3;
            int sc = (s ^ (r & 3)) * 8;               // inverse swizzle on source
            gll16(xb_b + (size_t)r * D + kofs + sc, &Ah[bb][(w * 128 + p * 64) * 8]);
        }
        int c = w * 64 + lane;                        // 0..511
        int r = c >> 2, s = c & 3;
        int sc = (s ^ (r & 3)) * 8;
        gll16(wz_b + (size_t)r * D + kofs + sc, &Bt[bb][(w * 64) * 8]);
    };

    stage(0, 0);
    __syncthreads();

    for (int kt = 0; kt < NKT; ++kt) {
        const int cur = kt & 1;
        if (kt < NKT - 1) stage(kt + 1, cur ^ 1);

        #pragma unroll
        for (int half = 0; half < 2; ++half) {
            bf16x8 bfr[4];
            #pragma unroll
            for (int ni4 = 0; ni4 < 4; ++ni4) {
                int brow = (half * 4 + ni4) * 16 + l15;
                bfr[ni4] = *(const bf16x8*)&Bt[cur][brow * GBK + ((lg ^ (brow & 3)) * 8)];
            }
            #pragma unroll
            for (int mi = 0; mi < 2; ++mi) {
                int arow = w * 32 + mi * 16 + l15;
                int so = (lg ^ (arow & 3)) * 8;
                bf16x8 ah = *(const bf16x8*)&Ah[cur][arow * GBK + so];
                #pragma unroll
                for (int ni4 = 0; ni4 < 4; ++ni4)
                    acc[mi][half * 4 + ni4] = __builtin_amdgcn_mfma_f32_16x16x32_bf16(
                        ah, bfr[ni4], acc[mi][half * 4 + ni4], 0, 0, 0);
            }
        }
        __syncthreads();
    }

    float bv8[8];
    #pragma unroll
    for (int ni = 0; ni < 8; ++ni) bv8[ni] = bias[n0 + ni * 16 + l15];

    if (zi < 2) {
        u16* __restrict__ dst = (zi == 0) ? wsq : wsk;
        #pragma unroll
        for (int mi = 0; mi < 2; ++mi) {
            #pragma unroll
            for (int r = 0; r < 4; ++r) {
                int m = m0 + w * 32 + mi * 16 + lg * 4 + r;
                int bb = m >> 11, s = m & 2047;
                #pragma unroll
                for (int ni = 0; ni < 8; ++ni) {
                    int h = h0 + (ni >> 2);
                    int hd = (ni & 3) * 16 + l15;
                    dst[((size_t)(bb * H + h) * S + s) * HD + hd] =
                        f2bf(acc[mi][ni][r] + bv8[ni]);
                }
            }
        }
    } else {
        // v -> transposed [bh][hd][s]; 4 consecutive s per lane -> uint2
        #pragma unroll
        for (int mi = 0; mi < 2; ++mi) {
            int mb = m0 + w * 32 + mi * 16 + lg * 4;
            int bb = mb >> 11, s0 = mb & 2047;
            #pragma unroll
            for (int ni = 0; ni < 8; ++ni) {
                int h = h0 + (ni >> 2);
                int hd = (ni & 3) * 16 + l15;
                u16 e0 = f2bf(acc[mi][ni][0] + bv8[ni]);
                u16 e1 = f2bf(acc[mi][ni][1] + bv8[ni]);
                u16 e2 = f2bf(acc[mi][ni][2] + bv8[ni]);
                u16 e3 = f2bf(acc[mi][ni][3] + bv8[ni]);
                *(uint2*)(wvt + ((size_t)(bb * H + h) * HD + hd) * S + s0) =
                    make_uint2(pack2(e0, e1), pack2(e2, e3));
            }
        }
    }
}

// ---------------------------------------------------------------------------
// Kernel 2: fused attention (swapped QK^T, 2-pass, QB=256, 16 waves, T5
// setprio, nt probs stores, R14's counted-vmcnt 3-deep pipeline). R15:
// exp2-fold -- p = 2^(s*log2e + log2(1/l)) via raw v_exp_f32: 2 VALU/elem
// instead of 3 (drops the per-element inv_l multiply).
// ---------------------------------------------------------------------------
__global__ __launch_bounds__(1024) void attn_fused_kernel(
    const u16* __restrict__ qg, const u16* __restrict__ kg,
    const u16* __restrict__ vtg, float* __restrict__ probs,
    float* __restrict__ out)
{
    // XCD-aware remap (nwg = 512, divisible by 8 -> bijective; chunk 64)
    const int lin = blockIdx.x;
    const int swz = (lin & 7) * 64 + (lin >> 3);
    const int bh = swz >> 3;                  // 8 q-blocks per bh
    const int m0 = (swz & 7) * 256;

    const int b = bh >> 4, h = bh & 15;
    const int tid = threadIdx.x;
    const int w = tid >> 6, lane = tid & 63;  // 16 waves
    const int l15 = lane & 15, lg = lane >> 4;

    const u16* __restrict__ qb  = qg  + (size_t)bh * S * HD;
    const u16* __restrict__ kbp = kg  + (size_t)bh * S * HD;
    const u16* __restrict__ vtb = vtg + (size_t)bh * HD * S;
    float* __restrict__ pb = probs + ((size_t)bh * S + m0) * (size_t)S;

    __shared__ __align__(16) u16 Ks[3][64 * 64];     // 24 KB
    __shared__ __align__(16) u16 Vts[3][64 * 64];    // 24 KB
    __shared__ __align__(16) u16 Pl[16][16 * 64];    // 32 KB, wave-private

    bf16x8 aq[2];
    {
        const u16* qr = qb + (size_t)(m0 + w * 16 + l15) * HD + lg * 8;
        aq[0] = *(const bf16x8*)(qr);
        aq[1] = *(const bf16x8*)(qr + 32);
    }

    // 512 chunks per 64x64 tile; waves 0-7 stage K, waves 8-15 stage V.
    auto stageK = [&](int t, int bb) {
        if (w < 8) {
            int c = w * 64 + lane;
            int r = c >> 3, s = c & 7;
            int sc = (s ^ (r & 7)) * 8;
            gll16(kbp + (size_t)(t * 64 + r) * 64 + sc, &Ks[bb][(w * 64) * 8]);
        }
    };
    auto stageV = [&](int t, int bb) {
        if (w >= 8) {
            int c = (w - 8) * 64 + lane;
            int r = c >> 3, s = c & 7;
            int sc = (s ^ (r & 7)) * 8;
            gll16(vtb + (size_t)r * S + t * 64 + sc, &Vts[bb][((w - 8) * 64) * 8]);
        }
    };

    // ------------------------- Pass A: row sums -------------------------
    float lacc = 0.f;
    stageK(0, 0);
    stageK(1, 1);
    asm volatile("s_waitcnt vmcnt(1)" ::: "memory");   // tile-0 K landed
    __builtin_amdgcn_s_barrier();
    __builtin_amdgcn_sched_barrier(0);

    {
        int cur = 0, stg = 2;
        for (int t = 0; t < 32; ++t) {
            if (t < 30) stageK(t + 2, stg);
            f32x4 acc[4];
            #pragma unroll
            for (int n = 0; n < 4; ++n) acc[n] = (f32x4){0.f, 0.f, 0.f, 0.f};
            __builtin_amdgcn_s_setprio(1);
            #pragma unroll
            for (int n = 0; n < 4; ++n) {
                #pragma unroll
                for (int kk = 0; kk < 2; ++kk) {
                    int row = n * 16 + l15;
                    int sl = (kk * 4 + lg) ^ (row & 7);
                    bf16x8 bk_ = *(const bf16x8*)&Ks[cur][row * 64 + sl * 8];
                    // SWAPPED: A = K rows, B = Q rows -> D[k][q], q = col = l15
                    acc[n] = __builtin_amdgcn_mfma_f32_16x16x32_bf16(bk_, aq[kk], acc[n], 0, 0, 0);
                }
            }
            __builtin_amdgcn_s_setprio(0);
            #pragma unroll
            for (int n = 0; n < 4; ++n)
                #pragma unroll
                for (int r = 0; r < 4; ++r)
                    lacc += __expf(acc[n][r]);
            // wait own t+1 K load (1 newer op = t+2's), publish, fence.
            if (t < 30)      asm volatile("s_waitcnt vmcnt(1)" ::: "memory");
            else if (t == 30) asm volatile("s_waitcnt vmcnt(0)" ::: "memory");
            __builtin_amdgcn_s_barrier();
            __builtin_amdgcn_sched_barrier(0);
            cur = (cur == 2) ? 0 : cur + 1;
            stg = (stg == 2) ? 0 : stg + 1;
        }
    }

    lacc += __shfl_xor(lacc, 16, 64);
    lacc += __shfl_xor(lacc, 32, 64);
    const float log2il = -log2f(lacc);        // fold 1/l into the exp2 arg

    // --------------------- Pass B: probs + PV ---------------------
    f32x4 accO[4];
    #pragma unroll
    for (int n = 0; n < 4; ++n) accO[n] = (f32x4){0.f, 0.f, 0.f, 0.f};

    stageK(0, 0); stageV(0, 0);
    stageK(1, 1); stageV(1, 1);
    asm volatile("s_waitcnt vmcnt(1)" ::: "memory");   // tile-0 K/V landed
    __builtin_amdgcn_s_barrier();
    __builtin_amdgcn_sched_barrier(0);

    float* pqrow = pb + (size_t)(w * 16 + l15) * S + lg * 4;   // this lane's q-row

    {
        int cur = 0, stg = 2;
        for (int t = 0; t < 32; ++t) {
            if (t < 30) { stageK(t + 2, stg); stageV(t + 2, stg); }

            f32x4 acc[4];
            #pragma unroll
            for (int n = 0; n < 4; ++n) acc[n] = (f32x4){0.f, 0.f, 0.f, 0.f};
            __builtin_amdgcn_s_setprio(1);
            #pragma unroll
            for (int n = 0; n < 4; ++n) {
                #pragma unroll
                for (int kk = 0; kk < 2; ++kk) {
                    int row = n * 16 + l15;
                    int sl = (kk * 4 + lg) ^ (row & 7);
                    bf16x8 bk_ = *(const bf16x8*)&Ks[cur][row * 64 + sl * 8];
                    acc[n] = __builtin_amdgcn_mfma_f32_16x16x32_bf16(bk_, aq[kk], acc[n], 0, 0, 0);
                }
            }
            __builtin_amdgcn_s_setprio(0);

            // p = 2^(s*log2e + log2il) : lane owns q-row l15
            #pragma unroll
            for (int n = 0; n < 4; ++n) {
                float e0 = fexp2(fmaf(acc[n][0], 1.44269504089f, log2il));
                float e1 = fexp2(fmaf(acc[n][1], 1.44269504089f, log2il));
                float e2 = fexp2(fmaf(acc[n][2], 1.44269504089f, log2il));
                float e3 = fexp2(fmaf(acc[n][3], 1.44269504089f, log2il));
                f32x4 p4 = (f32x4){e0, e1, e2, e3};
                __builtin_nontemporal_store(p4, (f32x4*)(pqrow + t * 64 + n * 16));
                uint2 pk2 = make_uint2(pack2(f2bf(e0), f2bf(e1)),
                                       pack2(f2bf(e2), f2bf(e3)));
                int s16 = (2 * n + (lg >> 1)) ^ (l15 & 7);
                *(uint2*)&Pl[w][l15 * 64 + s16 * 8 + (lg & 1) * 4] = pk2;
            }

            // PV A-frags straight from wave-private P_lds (row = q = l15)
            bf16x8 af[2];
            #pragma unroll
            for (int kk2 = 0; kk2 < 2; ++kk2) {
                int s16 = (kk2 * 4 + lg) ^ (l15 & 7);
                af[kk2] = *(const bf16x8*)&Pl[w][l15 * 64 + s16 * 8];
            }

            __builtin_amdgcn_s_setprio(1);
            #pragma unroll
            for (int n = 0; n < 4; ++n) {
                #pragma unroll
                for (int kk2 = 0; kk2 < 2; ++kk2) {
                    int row = n * 16 + l15;
                    int sl = (kk2 * 4 + lg) ^ (row & 7);
                    bf16x8 bv = *(const bf16x8*)&Vts[cur][row * 64 + sl * 8];
                    accO[n] = __builtin_amdgcn_mfma_f32_16x16x32_bf16(af[kk2], bv, accO[n], 0, 0, 0);
                }
            }
            __builtin_amdgcn_s_setprio(0);

            // wait own t+1 load; newer ops = {1 prefetch, 4 nt stores} -> 5.
            if (t < 30)      asm volatile("s_waitcnt vmcnt(5)" ::: "memory");
            else if (t == 30) asm volatile("s_waitcnt vmcnt(4)" ::: "memory");
            __builtin_amdgcn_s_barrier();
            __builtin_amdgcn_sched_barrier(0);
            cur = (cur == 2) ? 0 : cur + 1;
            stg = (stg == 2) ? 0 : stg + 1;
        }
    }

    // epilogue: out[b][m0 + w*16 + lg*4 + r][h*64 + n*16 + l15]
    #pragma unroll
    for (int n = 0; n < 4; ++n)
        #pragma unroll
        for (int r = 0; r < 4; ++r)
            out[((size_t)b * S + m0 + w * 16 + lg * 4 + r) * D + h * HD + n * 16 + l15] =
                accO[n][r];
}

// ---------------------------------------------------------------------------
extern "C" void kernel_launch(void* const* d_in, const int* in_sizes, int n_in,
                              void* d_out, int out_size, void* d_ws, size_t ws_size,
                              hipStream_t stream)
{
    const float* x  = (const float*)d_in[0];
    const float* Wq = (const float*)d_in[1];
    const float* bq = (const float*)d_in[2];
    const float* Wk = (const float*)d_in[3];
    const float* bk = (const float*)d_in[4];
    const float* Wv = (const float*)d_in[5];
    const float* bv = (const float*)d_in[6];

    float* out   = (float*)d_out;               // [B,S,D]
    float* probs = out + (size_t)B * S * D;     // [B,H,S,S]

    u16* wsq = (u16*)d_ws;                      // bf16 q [B,H,S,HD]
    u16* wsk = wsq + TEN;                       // bf16 k [B,H,S,HD]
    u16* wvt = wsk + TEN;                       // bf16 v^T [B,H,HD,S]
    u16* xbf = wvt + TEN;                       // bf16 x [M,D]
    u16* wbf = xbf + TEN;                       // bf16 Wq|Wk|Wv [3,D,D]
    (void)ws_size;                              // needs (4*TEN + 3*D*D)*2 ~= 73.4 MB

    dim3 gc((unsigned)((NX8 + 3 * NW8 + 255) / 256));
    convert_kernel<<<gc, 256, 0, stream>>>(x, Wq, Wk, Wv, xbf, wbf);

    qkv_proj_kernel<<<dim3(768), 512, 0, stream>>>(xbf, wbf, bq, bk, bv,
                                                   wsq, wsk, wvt);

    attn_fused_kernel<<<dim3(512), 1024, 0, stream>>>(wsq, wsk, wvt, probs, out);
}

// Round 16
// 419.512 us; speedup vs baseline: 1.0323x; 1.0323x over previous
//
#include <hip/hip_runtime.h>
#include <hip/hip_bf16.h>

typedef unsigned short u16;
typedef unsigned int   u32;

// Problem constants: B=4, S=2048, D=1024, H=16, HD=64
constexpr int B = 4, S = 2048, D = 1024, H = 16, HD = 64;
constexpr int M = B * S;                    // 8192
constexpr size_t TEN = (size_t)M * D;       // elems per q/k/v tensor (8.4M)

using bf16x8 = __attribute__((ext_vector_type(8))) short;
using f32x4  = __attribute__((ext_vector_type(4))) float;

__device__ __forceinline__ u16 f2bf(float f) {      // RNE f32 -> bf16
    u32 u = __float_as_uint(f);
    u += 0x7fffu + ((u >> 16) & 1u);
    return (u16)(u >> 16);
}
__device__ __forceinline__ u32 pack2(u16 a, u16 b) { return (u32)a | ((u32)b << 16); }

// Async global->LDS, 16B per lane. LDS dest is the WAVE-UNIFORM base;
// HW writes lane i at base + i*16. Source addr is per-lane.
__device__ __forceinline__ void gll16(const u16* gsrc, u16* ldst) {
    __builtin_amdgcn_global_load_lds(
        (const __attribute__((address_space(1))) u32*)gsrc,
        (__attribute__((address_space(3))) u32*)ldst,
        16, 0, 0);
}

// ---------------------------------------------------------------------------
// Kernel 0: convert x -> bf16 and Wq|Wk|Wv -> bf16. (R13 version.)
// ---------------------------------------------------------------------------
constexpr size_t NX8 = TEN / 8;             // 1,048,576 x-chunks
constexpr size_t NW8 = (size_t)D * D / 8;   // 131,072 chunks per W

__global__ __launch_bounds__(256) void convert_kernel(
    const float* __restrict__ x,
    const float* __restrict__ Wq, const float* __restrict__ Wk,
    const float* __restrict__ Wv,
    u16* __restrict__ xbf, u16* __restrict__ wbf)
{
    size_t i = (size_t)blockIdx.x * 256 + threadIdx.x;
    if (i < NX8) {
        float4 f0 = *((const float4*)x + i * 2);
        float4 f1 = *((const float4*)x + i * 2 + 1);
        float f[8] = {f0.x, f0.y, f0.z, f0.w, f1.x, f1.y, f1.z, f1.w};
        u16 h[8];
        #pragma unroll
        for (int e = 0; e < 8; ++e) h[e] = f2bf(f[e]);
        *(uint4*)(xbf + i * 8) = make_uint4(pack2(h[0],h[1]), pack2(h[2],h[3]),
                                            pack2(h[4],h[5]), pack2(h[6],h[7]));
    } else if (i < NX8 + 3 * NW8) {
        size_t j = i - NX8;
        const float* Wsrc;
        size_t jj;
        if (j < NW8)            { Wsrc = Wq; jj = j; }
        else if (j < 2 * NW8)   { Wsrc = Wk; jj = j - NW8; }
        else                    { Wsrc = Wv; jj = j - 2 * NW8; }
        float4 f0 = *((const float4*)Wsrc + jj * 2);
        float4 f1 = *((const float4*)Wsrc + jj * 2 + 1);
        float f[8] = {f0.x, f0.y, f0.z, f0.w, f1.x, f1.y, f1.z, f1.w};
        u16 h[8];
        #pragma unroll
        for (int e = 0; e < 8; ++e) h[e] = f2bf(f[e]);
        *(uint4*)(wbf + j * 8) = make_uint4(pack2(h[0],h[1]), pack2(h[2],h[3]),
                                            pack2(h[4],h[5]), pack2(h[6],h[7]));
    }
}

// ---------------------------------------------------------------------------
// Kernel 1: QKV projection via bf16 MFMA. (R13/R14 version: GBM=128, 4 waves,
// (256,3), XCD-chunk 1D grid, gll16 staging — measured best.)
// ---------------------------------------------------------------------------
constexpr int GBM = 128, GBN = 128, GBK = 32;
constexpr int NKT = D / GBK;                 // 32 k-tiles

__global__ __launch_bounds__(256, 3) void qkv_proj_kernel(
    const u16* __restrict__ xbf, const u16* __restrict__ wbf,
    const float* __restrict__ bq, const float* __restrict__ bk,
    const float* __restrict__ bv,
    u16* __restrict__ wsq, u16* __restrict__ wsk, u16* __restrict__ wvt)
{
    const int lin    = blockIdx.x;            // 0..1535
    const int xcd    = lin & 7;
    const int local  = lin >> 3;              // 0..191
    const int wg     = local >> 3;            // 0..23 : (zi,ny)
    const int zi     = wg >> 3;               // 0..2
    const int ny     = wg & 7;                // 0..7
    const int mstrip = xcd * 8 + (local & 7); // 0..63

    const u16* __restrict__ Wz = wbf + (size_t)zi * D * D;
    const float* __restrict__ bias = (zi == 0) ? bq : (zi == 1) ? bk : bv;

    const int m0 = mstrip * GBM;
    const int n0 = ny * GBN;                  // spans heads n0/64, n0/64+1
    const int h0 = n0 >> 6;
    const int tid = threadIdx.x;
    const int w = tid >> 6, lane = tid & 63;
    const int l15 = lane & 15, lg = lane >> 4;

    __shared__ __align__(16) u16 Ah[2][GBM * GBK];   // 2 x 8KB
    __shared__ __align__(16) u16 Bt[2][GBN * GBK];   // 2 x 8KB

    const u16* __restrict__ xb_b = xbf + (size_t)m0 * D;
    const u16* __restrict__ wz_b = Wz + (size_t)n0 * D;

    f32x4 acc[2][8];
    #pragma unroll
    for (int mi = 0; mi < 2; ++mi)
        #pragma unroll
        for (int ni = 0; ni < 8; ++ni) acc[mi][ni] = (f32x4){0.f,0.f,0.f,0.f};

    auto stage = [&](int kt, int bb) {
        const int kofs = kt * GBK;
        #pragma unroll
        for (int p = 0; p < 2; ++p) {
            int c = w * 128 + p * 64 + lane;
            int r = c >> 2, s = c & 3;
            int sc = (s ^ (r & 3)) * 8;               // inverse swizzle on source
            const size_t go = (size_t)r * D + kofs + sc;
            gll16(xb_b + go, &Ah[bb][(w * 128 + p * 64) * 8]);
            gll16(wz_b + go, &Bt[bb][(w * 128 + p * 64) * 8]);
        }
    };

    stage(0, 0);
    __syncthreads();

    for (int kt = 0; kt < NKT; ++kt) {
        const int cur = kt & 1;
        if (kt < NKT - 1) stage(kt + 1, cur ^ 1);

        #pragma unroll
        for (int half = 0; half < 2; ++half) {
            bf16x8 bfr[4];
            #pragma unroll
            for (int ni4 = 0; ni4 < 4; ++ni4) {
                int brow = (half * 4 + ni4) * 16 + l15;
                bfr[ni4] = *(const bf16x8*)&Bt[cur][brow * GBK + ((lg ^ (brow & 3)) * 8)];
            }
            #pragma unroll
            for (int mi = 0; mi < 2; ++mi) {
                int arow = w * 32 + mi * 16 + l15;
                int so = (lg ^ (arow & 3)) * 8;
                bf16x8 ah = *(const bf16x8*)&Ah[cur][arow * GBK + so];
                #pragma unroll
                for (int ni4 = 0; ni4 < 4; ++ni4)
                    acc[mi][half * 4 + ni4] = __builtin_amdgcn_mfma_f32_16x16x32_bf16(
                        ah, bfr[ni4], acc[mi][half * 4 + ni4], 0, 0, 0);
            }
        }
        __syncthreads();
    }

    float bv8[8];
    #pragma unroll
    for (int ni = 0; ni < 8; ++ni) bv8[ni] = bias[n0 + ni * 16 + l15];

    if (zi < 2) {
        u16* __restrict__ dst = (zi == 0) ? wsq : wsk;
        #pragma unroll
        for (int mi = 0; mi < 2; ++mi) {
            #pragma unroll
            for (int r = 0; r < 4; ++r) {
                int m = m0 + w * 32 + mi * 16 + lg * 4 + r;
                int bb = m >> 11, s = m & 2047;
                #pragma unroll
                for (int ni = 0; ni < 8; ++ni) {
                    int h = h0 + (ni >> 2);
                    int hd = (ni & 3) * 16 + l15;
                    dst[((size_t)(bb * H + h) * S + s) * HD + hd] =
                        f2bf(acc[mi][ni][r] + bv8[ni]);
                }
            }
        }
    } else {
        #pragma unroll
        for (int mi = 0; mi < 2; ++mi) {
            int mb = m0 + w * 32 + mi * 16 + lg * 4;
            int bb = mb >> 11, s0 = mb & 2047;
            #pragma unroll
            for (int ni = 0; ni < 8; ++ni) {
                int h = h0 + (ni >> 2);
                int hd = (ni & 3) * 16 + l15;
                u16 e0 = f2bf(acc[mi][ni][0] + bv8[ni]);
                u16 e1 = f2bf(acc[mi][ni][1] + bv8[ni]);
                u16 e2 = f2bf(acc[mi][ni][2] + bv8[ni]);
                u16 e3 = f2bf(acc[mi][ni][3] + bv8[ni]);
                *(uint2*)(wvt + ((size_t)(bb * H + h) * HD + hd) * S + s0) =
                    make_uint2(pack2(e0, e1), pack2(e2, e3));
            }
        }
    }
}

// ---------------------------------------------------------------------------
// Kernel 2: fused attention (swapped QK^T, 2-pass, QB=256, 16 waves, T5
// setprio, nt probs stores, counted-vmcnt 3-deep pipeline). (R14 version —
// measured best.)
// ---------------------------------------------------------------------------
__global__ __launch_bounds__(1024) void attn_fused_kernel(
    const u16* __restrict__ qg, const u16* __restrict__ kg,
    const u16* __restrict__ vtg, float* __restrict__ probs,
    float* __restrict__ out)
{
    // XCD-aware remap (nwg = 512, divisible by 8 -> bijective; chunk 64)
    const int lin = blockIdx.x;
    const int swz = (lin & 7) * 64 + (lin >> 3);
    const int bh = swz >> 3;                  // 8 q-blocks per bh
    const int m0 = (swz & 7) * 256;

    const int b = bh >> 4, h = bh & 15;
    const int tid = threadIdx.x;
    const int w = tid >> 6, lane = tid & 63;  // 16 waves
    const int l15 = lane & 15, lg = lane >> 4;

    const u16* __restrict__ qb  = qg  + (size_t)bh * S * HD;
    const u16* __restrict__ kbp = kg  + (size_t)bh * S * HD;
    const u16* __restrict__ vtb = vtg + (size_t)bh * HD * S;
    float* __restrict__ pb = probs + ((size_t)bh * S + m0) * (size_t)S;

    __shared__ __align__(16) u16 Ks[3][64 * 64];     // 24 KB
    __shared__ __align__(16) u16 Vts[3][64 * 64];    // 24 KB
    __shared__ __align__(16) u16 Pl[16][16 * 64];    // 32 KB, wave-private

    bf16x8 aq[2];
    {
        const u16* qr = qb + (size_t)(m0 + w * 16 + l15) * HD + lg * 8;
        aq[0] = *(const bf16x8*)(qr);
        aq[1] = *(const bf16x8*)(qr + 32);
    }

    // 512 chunks per 64x64 tile; waves 0-7 stage K, waves 8-15 stage V.
    auto stageK = [&](int t, int bb) {
        if (w < 8) {
            int c = w * 64 + lane;
            int r = c >> 3, s = c & 7;
            int sc = (s ^ (r & 7)) * 8;
            gll16(kbp + (size_t)(t * 64 + r) * 64 + sc, &Ks[bb][(w * 64) * 8]);
        }
    };
    auto stageV = [&](int t, int bb) {
        if (w >= 8) {
            int c = (w - 8) * 64 + lane;
            int r = c >> 3, s = c & 7;
            int sc = (s ^ (r & 7)) * 8;
            gll16(vtb + (size_t)r * S + t * 64 + sc, &Vts[bb][((w - 8) * 64) * 8]);
        }
    };

    // ------------------------- Pass A: row sums -------------------------
    float lacc = 0.f;
    stageK(0, 0);
    stageK(1, 1);
    asm volatile("s_waitcnt vmcnt(1)" ::: "memory");   // tile-0 K landed
    __builtin_amdgcn_s_barrier();
    __builtin_amdgcn_sched_barrier(0);

    {
        int cur = 0, stg = 2;
        for (int t = 0; t < 32; ++t) {
            if (t < 30) stageK(t + 2, stg);
            f32x4 acc[4];
            #pragma unroll
            for (int n = 0; n < 4; ++n) acc[n] = (f32x4){0.f, 0.f, 0.f, 0.f};
            __builtin_amdgcn_s_setprio(1);
            #pragma unroll
            for (int n = 0; n < 4; ++n) {
                #pragma unroll
                for (int kk = 0; kk < 2; ++kk) {
                    int row = n * 16 + l15;
                    int sl = (kk * 4 + lg) ^ (row & 7);
                    bf16x8 bk_ = *(const bf16x8*)&Ks[cur][row * 64 + sl * 8];
                    // SWAPPED: A = K rows, B = Q rows -> D[k][q], q = col = l15
                    acc[n] = __builtin_amdgcn_mfma_f32_16x16x32_bf16(bk_, aq[kk], acc[n], 0, 0, 0);
                }
            }
            __builtin_amdgcn_s_setprio(0);
            #pragma unroll
            for (int n = 0; n < 4; ++n)
                #pragma unroll
                for (int r = 0; r < 4; ++r)
                    lacc += __expf(acc[n][r]);
            // wait own t+1 K load (1 newer op = t+2's), publish, fence.
            if (t < 30)      asm volatile("s_waitcnt vmcnt(1)" ::: "memory");
            else if (t == 30) asm volatile("s_waitcnt vmcnt(0)" ::: "memory");
            __builtin_amdgcn_s_barrier();
            __builtin_amdgcn_sched_barrier(0);
            cur = (cur == 2) ? 0 : cur + 1;
            stg = (stg == 2) ? 0 : stg + 1;
        }
    }

    lacc += __shfl_xor(lacc, 16, 64);
    lacc += __shfl_xor(lacc, 32, 64);
    const float inv_l = 1.f / lacc;          // row sum for q-row w*16+l15

    // --------------------- Pass B: probs + PV ---------------------
    f32x4 accO[4];
    #pragma unroll
    for (int n = 0; n < 4; ++n) accO[n] = (f32x4){0.f, 0.f, 0.f, 0.f};

    stageK(0, 0); stageV(0, 0);
    stageK(1, 1); stageV(1, 1);
    asm volatile("s_waitcnt vmcnt(1)" ::: "memory");   // tile-0 K/V landed
    __builtin_amdgcn_s_barrier();
    __builtin_amdgcn_sched_barrier(0);

    float* pqrow = pb + (size_t)(w * 16 + l15) * S + lg * 4;   // this lane's q-row

    {
        int cur = 0, stg = 2;
        for (int t = 0; t < 32; ++t) {
            if (t < 30) { stageK(t + 2, stg); stageV(t + 2, stg); }

            f32x4 acc[4];
            #pragma unroll
            for (int n = 0; n < 4; ++n) acc[n] = (f32x4){0.f, 0.f, 0.f, 0.f};
            __builtin_amdgcn_s_setprio(1);
            #pragma unroll
            for (int n = 0; n < 4; ++n) {
                #pragma unroll
                for (int kk = 0; kk < 2; ++kk) {
                    int row = n * 16 + l15;
                    int sl = (kk * 4 + lg) ^ (row & 7);
                    bf16x8 bk_ = *(const bf16x8*)&Ks[cur][row * 64 + sl * 8];
                    acc[n] = __builtin_amdgcn_mfma_f32_16x16x32_bf16(bk_, aq[kk], acc[n], 0, 0, 0);
                }
            }
            __builtin_amdgcn_s_setprio(0);

            // p = exp(s)/l : lane owns q-row l15, k = t*64 + n*16 + lg*4 + r
            #pragma unroll
            for (int n = 0; n < 4; ++n) {
                float e0 = __expf(acc[n][0]) * inv_l;
                float e1 = __expf(acc[n][1]) * inv_l;
                float e2 = __expf(acc[n][2]) * inv_l;
                float e3 = __expf(acc[n][3]) * inv_l;
                f32x4 p4 = (f32x4){e0, e1, e2, e3};
                __builtin_nontemporal_store(p4, (f32x4*)(pqrow + t * 64 + n * 16));
                uint2 pk2 = make_uint2(pack2(f2bf(e0), f2bf(e1)),
                                       pack2(f2bf(e2), f2bf(e3)));
                int s16 = (2 * n + (lg >> 1)) ^ (l15 & 7);
                *(uint2*)&Pl[w][l15 * 64 + s16 * 8 + (lg & 1) * 4] = pk2;
            }

            // PV A-frags straight from wave-private P_lds (row = q = l15)
            bf16x8 af[2];
            #pragma unroll
            for (int kk2 = 0; kk2 < 2; ++kk2) {
                int s16 = (kk2 * 4 + lg) ^ (l15 & 7);
                af[kk2] = *(const bf16x8*)&Pl[w][l15 * 64 + s16 * 8];
            }

            __builtin_amdgcn_s_setprio(1);
            #pragma unroll
            for (int n = 0; n < 4; ++n) {
                #pragma unroll
                for (int kk2 = 0; kk2 < 2; ++kk2) {
                    int row = n * 16 + l15;
                    int sl = (kk2 * 4 + lg) ^ (row & 7);
                    bf16x8 bv = *(const bf16x8*)&Vts[cur][row * 64 + sl * 8];
                    accO[n] = __builtin_amdgcn_mfma_f32_16x16x32_bf16(af[kk2], bv, accO[n], 0, 0, 0);
                }
            }
            __builtin_amdgcn_s_setprio(0);

            // wait own t+1 load; newer ops = {1 prefetch, 4 nt stores} -> 5.
            if (t < 30)      asm volatile("s_waitcnt vmcnt(5)" ::: "memory");
            else if (t == 30) asm volatile("s_waitcnt vmcnt(4)" ::: "memory");
            __builtin_amdgcn_s_barrier();
            __builtin_amdgcn_sched_barrier(0);
            cur = (cur == 2) ? 0 : cur + 1;
            stg = (stg == 2) ? 0 : stg + 1;
        }
    }

    // epilogue: out[b][m0 + w*16 + lg*4 + r][h*64 + n*16 + l15]
    #pragma unroll
    for (int n = 0; n < 4; ++n)
        #pragma unroll
        for (int r = 0; r < 4; ++r)
            out[((size_t)b * S + m0 + w * 16 + lg * 4 + r) * D + h * HD + n * 16 + l15] =
                accO[n][r];
}

// ---------------------------------------------------------------------------
extern "C" void kernel_launch(void* const* d_in, const int* in_sizes, int n_in,
                              void* d_out, int out_size, void* d_ws, size_t ws_size,
                              hipStream_t stream)
{
    const float* x  = (const float*)d_in[0];
    const float* Wq = (const float*)d_in[1];
    const float* bq = (const float*)d_in[2];
    const float* Wk = (const float*)d_in[3];
    const float* bk = (const float*)d_in[4];
    const float* Wv = (const float*)d_in[5];
    const float* bv = (const float*)d_in[6];

    float* out   = (float*)d_out;               // [B,S,D]
    float* probs = out + (size_t)B * S * D;     // [B,H,S,S]

    u16* wsq = (u16*)d_ws;                      // bf16 q [B,H,S,HD]
    u16* wsk = wsq + TEN;                       // bf16 k [B,H,S,HD]
    u16* wvt = wsk + TEN;                       // bf16 v^T [B,H,HD,S]
    u16* xbf = wvt + TEN;                       // bf16 x [M,D]
    u16* wbf = xbf + TEN;                       // bf16 Wq|Wk|Wv [3,D,D]
    (void)ws_size;                              // needs (4*TEN + 3*D*D)*2 ~= 73.4 MB

    dim3 gc((unsigned)((NX8 + 3 * NW8 + 255) / 256));
    convert_kernel<<<gc, 256, 0, stream>>>(x, Wq, Wk, Wv, xbf, wbf);

    qkv_proj_kernel<<<dim3(1536), 256, 0, stream>>>(xbf, wbf, bq, bk, bv,
                                                    wsq, wsk, wvt);

    attn_fused_kernel<<<dim3(512), 1024, 0, stream>>>(wsq, wsk, wvt, probs, out);
}